// Round 3
// baseline (179.681 us; speedup 1.0000x reference)
//
#include <hip/hip_runtime.h>

#define SEQ 512
#define HID 768
#define P2  46
#define BLK 256
#define WST 776    // full-K W row stride in shorts (16B-aligned rows; 2-way bank alias only)

typedef short bf16x8 __attribute__((ext_vector_type(8)));
typedef float f32x4  __attribute__((ext_vector_type(4)));

__device__ __forceinline__ unsigned short f2bf(float f) {
  union { float f; unsigned int u; } v; v.f = f;
  return (unsigned short)((v.u + 0x7FFFu + ((v.u >> 16) & 1u)) >> 16);
}

__global__ __launch_bounds__(BLK) void fused_kernel(const float* __restrict__ h,
                                                    const int* __restrict__ ids,
                                                    const int* __restrict__ mask,
                                                    const float* __restrict__ W,
                                                    const float* __restrict__ bias,
                                                    float* __restrict__ out) {
  // W resident for full K in bf16: 48 rows (46 real + 2 zero) x 776 stride = 74.5 KB
  __shared__ __align__(16) unsigned short wlds[48 * WST];
  __shared__ __align__(16) float s_lds[HID];   // h[b,i0,:] + h[b,i1,:]
  __shared__ float q_lds[48];

  const int tid  = threadIdx.x;
  const int lane = tid & 63, wv = tid >> 6;
  const int mr   = lane & 15, qd = lane >> 4;
  const int row0 = blockIdx.x * 64;            // flat row = b*512 + s
  const int b    = row0 >> 9;
  const int rowa = row0 + (wv << 4) + mr;
  const float* hrow = h + (size_t)rowa * HID + (qd << 3);

  // ---- stage W (bf16, full K) ----
  // zero pad rows 46,47
  for (int i = tid; i < WST; i += BLK)
    ((unsigned int*)(wlds + 46 * WST))[i] = 0u;
  for (int i = tid; i < (P2 * HID) / 4; i += BLK) {
    int f = i * 4;
    int r = f / HID;
    int c = f - r * HID;
    float4 w4 = *(const float4*)(W + (size_t)r * HID + c);
    ushort4 v;
    v.x = f2bf(w4.x); v.y = f2bf(w4.y); v.z = f2bf(w4.z); v.w = f2bf(w4.w);
    *(ushort4*)&wlds[r * WST + c] = v;
  }
  // ---- stage s = h[b,i0,:] + h[b,i1,:] (fp32) ----
  {
    int i0 = ids[b * 2 + 0], i1 = ids[b * 2 + 1];
    const float* r0 = h + ((size_t)b * SEQ + i0) * HID;
    const float* r1 = h + ((size_t)b * SEQ + i1) * HID;
    #pragma unroll
    for (int j = 0; j < HID / BLK; ++j) {
      int k = tid + j * BLK;
      s_lds[k] = r0[k] + r1[k];
    }
  }
  __syncthreads();

  // ---- q[p] = s . W[p,:] in exact fp32 (W from global/L2, float4) ----
  if (tid < P2 * 4) {
    int p = tid >> 2, kq = tid & 3;
    const float4* wp = (const float4*)(W + (size_t)p * HID + kq * 192);
    float acc = 0.f;
    #pragma unroll 8
    for (int j = 0; j < 48; ++j) {
      float4 w4 = wp[j];
      int k = kq * 192 + j * 4;
      acc += s_lds[k] * w4.x + s_lds[k + 1] * w4.y
           + s_lds[k + 2] * w4.z + s_lds[k + 3] * w4.w;
    }
    acc += __shfl_xor(acc, 1, 64);
    acc += __shfl_xor(acc, 2, 64);
    if (kq == 0) q_lds[p] = acc;
  }
  __syncthreads();

  // ---- main GEMM: direct reg A-loads, MFMA against LDS W ----
  f32x4 acc[3];
  #pragma unroll
  for (int nt = 0; nt < 3; ++nt) acc[nt] = f32x4{0.f, 0.f, 0.f, 0.f};

  #pragma unroll
  for (int half = 0; half < 2; ++half) {
    const float* hb = hrow + half * 384;
    float4 abuf[24];
    #pragma unroll
    for (int i = 0; i < 24; ++i)
      abuf[i] = *(const float4*)(hb + (i >> 1) * 32 + (i & 1) * 4);
    #pragma unroll
    for (int it = 0; it < 12; ++it) {
      bf16x8 a;
      {
        float4 x0 = abuf[2 * it], x1 = abuf[2 * it + 1];
        a[0] = (short)f2bf(x0.x); a[1] = (short)f2bf(x0.y);
        a[2] = (short)f2bf(x0.z); a[3] = (short)f2bf(x0.w);
        a[4] = (short)f2bf(x1.x); a[5] = (short)f2bf(x1.y);
        a[6] = (short)f2bf(x1.z); a[7] = (short)f2bf(x1.w);
      }
      #pragma unroll
      for (int nt = 0; nt < 3; ++nt) {
        bf16x8 bb = *(const bf16x8*)&wlds[((nt << 4) + mr) * WST
                                          + half * 384 + it * 32 + (qd << 3)];
        acc[nt] = __builtin_amdgcn_mfma_f32_16x16x32_bf16(a, bb, acc[nt], 0, 0, 0);
      }
    }
  }

  // ---- epilogue: C/D layout col = lane&15, row = quad*4 + reg ----
  int mrow[4];
  #pragma unroll
  for (int i = 0; i < 4; ++i)
    mrow[i] = mask[row0 + (wv << 4) + (qd << 2) + i];

  #pragma unroll
  for (int nt = 0; nt < 3; ++nt) {
    int p = (nt << 4) + mr;
    if (p < P2) {
      float bv = bias[p];
      float qv = q_lds[p];
      #pragma unroll
      for (int i = 0; i < 4; ++i) {
        int row = row0 + (wv << 4) + (qd << 2) + i;
        float x = acc[nt][i] + bv + (mrow[i] ? qv : 0.f);
        float sg = 1.f / (1.f + __expf(-x));
        sg *= sg; sg *= sg;               // sigmoid^4
        out[(size_t)row * P2 + p] = sg;
      }
    }
  }
}

extern "C" void kernel_launch(void* const* d_in, const int* in_sizes, int n_in,
                              void* d_out, int out_size, void* d_ws, size_t ws_size,
                              hipStream_t stream) {
  const float* h    = (const float*)d_in[0];   // [64,512,768] fp32
  const int*   ids  = (const int*)d_in[1];     // [64,2]
  const int*   mask = (const int*)d_in[2];     // [64,512]
  const float* W    = (const float*)d_in[3];   // [46,768]
  const float* bias = (const float*)d_in[4];   // [46]
  float* out = (float*)d_out;                  // [64,512,46] fp32

  fused_kernel<<<dim3((64 * SEQ) / 64), BLK, 0, stream>>>(h, ids, mask, W, bias, out);
}

// Round 4
// 169.524 us; speedup vs baseline: 1.0599x; 1.0599x over previous
//
#include <hip/hip_runtime.h>

#define SEQ 512
#define HID 768
#define P2  46
#define BLK 512
#define MT  128          // rows per block
#define KC  32           // K chunk
#define NC  (HID / KC)   // 24 chunks
#define WST 776          // W LDS row stride in shorts (388 dw == 4 mod 32 -> uniform banks)

typedef short bf16x8 __attribute__((ext_vector_type(8)));
typedef float f32x4  __attribute__((ext_vector_type(4)));

__device__ __forceinline__ unsigned short f2bf(float f) {
  union { float f; unsigned int u; } v; v.f = f;
  return (unsigned short)((v.u + 0x7FFFu + ((v.u >> 16) & 1u)) >> 16);
}

__device__ __forceinline__ void gl_lds16(const float* g, void* l) {
  // async global->LDS DMA: lane i's 16B lands at (uniform l) + i*16
  __builtin_amdgcn_global_load_lds(
      (const __attribute__((address_space(1))) void*)g,
      (__attribute__((address_space(3))) void*)l, 16, 0, 0);
}

__global__ __launch_bounds__(BLK, 2) void fused_kernel(const float* __restrict__ h,
                                                       const int* __restrict__ ids,
                                                       const int* __restrict__ mask,
                                                       const float* __restrict__ W,
                                                       const float* __restrict__ bias,
                                                       float* __restrict__ out) {
  // W full-K bf16: 48 rows (46 real + 2 garbage-ok) x 776 = 74.5 KB
  __shared__ __align__(16) unsigned short wlds[48 * WST];
  // h tile: 4 buffers x (128 rows x 32 floats) = 64 KB, 16B-XOR-swizzled
  __shared__ __align__(16) float hbuf[4][MT * KC];
  __shared__ __align__(16) float s_lds[HID];
  __shared__ float q_lds[48];

  const int tid  = threadIdx.x;
  const int lane = tid & 63, wv = tid >> 6;
  const int mr   = lane & 15, qd = lane >> 4;
  const int row0 = blockIdx.x * MT;            // flat row = b*512 + s ; 4 blocks/batch
  const int b    = row0 >> 9;

  // ---- wave-self-contained async staging of chunk c (wave wv loads its own 16 rows) ----
  auto issueChunk = [&](int c) {
    int buf = c & 3;
    #pragma unroll
    for (int j = 0; j < 2; ++j) {
      int sb  = (wv << 7) + (j << 6);          // slot base (64 slots / call)
      int s   = sb + lane;
      int row = s >> 3;                        // local row 0..127 (wave's own 16)
      int cc  = (s & 7) ^ (row & 7);           // inverse of XOR swizzle (involution)
      const float* g = h + (size_t)(row0 + row) * HID + c * KC + (cc << 2);
      gl_lds16(g, (void*)&hbuf[buf][sb << 2]); // uniform base; lane lands at slot sb+lane
    }
  };

  // prefetch 3 chunks before prologue staging
  issueChunk(0); issueChunk(1); issueChunk(2);

  // ---- stage W (bf16, full K) ----
  for (int i = tid; i < (2 * WST) / 2; i += BLK)        // zero rows 46,47
    ((unsigned int*)(wlds + 46 * WST))[i] = 0u;
  for (int i = tid; i < (P2 * HID) / 4; i += BLK) {
    int r  = i / 192;                                   // 192 float4 per row
    int c0 = (i - r * 192) * 4;
    float4 w4 = *(const float4*)(W + (size_t)r * HID + c0);
    ushort4 v;
    v.x = f2bf(w4.x); v.y = f2bf(w4.y); v.z = f2bf(w4.z); v.w = f2bf(w4.w);
    *(ushort4*)&wlds[r * WST + c0] = v;
  }
  // ---- stage s = h[b,i0,:] + h[b,i1,:] (fp32) ----
  {
    int i0 = ids[b * 2 + 0], i1 = ids[b * 2 + 1];
    const float* r0 = h + ((size_t)b * SEQ + i0) * HID;
    const float* r1 = h + ((size_t)b * SEQ + i1) * HID;
    for (int k = tid; k < HID; k += BLK) s_lds[k] = r0[k] + r1[k];
  }
  __syncthreads();

  // ---- q[p] = s . W[p,:] in exact fp32 (W float4 from L2) ----
  if (tid < P2 * 4) {
    int p = tid >> 2, kq = tid & 3;
    const float4* wp = (const float4*)(W + (size_t)p * HID + kq * 192);
    float acc = 0.f;
    #pragma unroll 8
    for (int j = 0; j < 48; ++j) {
      float4 w4 = wp[j];
      int k = kq * 192 + j * 4;
      acc += s_lds[k] * w4.x + s_lds[k + 1] * w4.y
           + s_lds[k + 2] * w4.z + s_lds[k + 3] * w4.w;
    }
    acc += __shfl_xor(acc, 1, 64);
    acc += __shfl_xor(acc, 2, 64);
    if (kq == 0) q_lds[p] = acc;
  }
  __syncthreads();

  // ---- barrier-free K-loop: each wave consumes only its own staged rows ----
  f32x4 acc[3];
  #pragma unroll
  for (int nt = 0; nt < 3; ++nt) acc[nt] = f32x4{0.f, 0.f, 0.f, 0.f};

  const int rA   = (wv << 4) + mr;     // this lane's A-row (local)
  const int base = (rA & 15) * 8 + (wv << 7);  // slot base of row = rA*8
  const int r7   = mr & 7;

  #pragma unroll
  for (int c = 0; c < NC; ++c) {
    // wait for issue(c) to land; keep later chunks in flight
    const int fut = NC - 1 - c;        // future chunks still outstanding
    if (fut >= 2)      asm volatile("s_waitcnt vmcnt(4)" ::: "memory");
    else if (fut == 1) asm volatile("s_waitcnt vmcnt(2)" ::: "memory");
    else               asm volatile("s_waitcnt vmcnt(0)" ::: "memory");

    const float* hb = &hbuf[c & 3][0];
    int cc0 = qd << 1;
    float4 x0 = *(const float4*)&hb[(base + (cc0 ^ r7)) << 2];
    float4 x1 = *(const float4*)&hb[(base + ((cc0 + 1) ^ r7)) << 2];
    bf16x8 a;
    a[0] = (short)f2bf(x0.x); a[1] = (short)f2bf(x0.y);
    a[2] = (short)f2bf(x0.z); a[3] = (short)f2bf(x0.w);
    a[4] = (short)f2bf(x1.x); a[5] = (short)f2bf(x1.y);
    a[6] = (short)f2bf(x1.z); a[7] = (short)f2bf(x1.w);
    #pragma unroll
    for (int nt = 0; nt < 3; ++nt) {
      bf16x8 bb = *(const bf16x8*)&wlds[((nt << 4) + mr) * WST + c * KC + (qd << 3)];
      acc[nt] = __builtin_amdgcn_mfma_f32_16x16x32_bf16(a, bb, acc[nt], 0, 0, 0);
    }
    if (c + 3 < NC) issueChunk(c + 3);
  }

  // ---- epilogue: C/D layout col = lane&15, row = quad*4 + reg ----
  int mrow[4];
  #pragma unroll
  for (int i = 0; i < 4; ++i)
    mrow[i] = mask[row0 + (wv << 4) + (qd << 2) + i];

  #pragma unroll
  for (int nt = 0; nt < 3; ++nt) {
    int p = (nt << 4) + mr;
    if (p < P2) {
      float bv = bias[p];
      float qv = q_lds[p];
      #pragma unroll
      for (int i = 0; i < 4; ++i) {
        int row = row0 + (wv << 4) + (qd << 2) + i;
        float x = acc[nt][i] + bv + (mrow[i] ? qv : 0.f);
        float sg = 1.f / (1.f + __expf(-x));
        sg *= sg; sg *= sg;               // sigmoid^4
        out[(size_t)row * P2 + p] = sg;
      }
    }
  }
}

extern "C" void kernel_launch(void* const* d_in, const int* in_sizes, int n_in,
                              void* d_out, int out_size, void* d_ws, size_t ws_size,
                              hipStream_t stream) {
  const float* h    = (const float*)d_in[0];   // [64,512,768] fp32
  const int*   ids  = (const int*)d_in[1];     // [64,2]
  const int*   mask = (const int*)d_in[2];     // [64,512]
  const float* W    = (const float*)d_in[3];   // [46,768]
  const float* bias = (const float*)d_in[4];   // [46]
  float* out = (float*)d_out;                  // [64,512,46] fp32

  fused_kernel<<<dim3((64 * SEQ) / MT), BLK, 0, stream>>>(h, ids, mask, W, bias, out);
}

// Round 5
// 163.450 us; speedup vs baseline: 1.0993x; 1.0372x over previous
//
#include <hip/hip_runtime.h>

#define SEQ 512
#define HID 768
#define P2  46
#define BLK 1024
#define MT  128          // rows per block
#define KC  32           // floats per K-chunk
#define HK  12           // chunks per K-half (24 total, split across wave pairs)
#define WST 776          // W LDS row stride in shorts (388 dw == 4 mod 32 -> 2-way max)

typedef short bf16x8 __attribute__((ext_vector_type(8)));
typedef float f32x4  __attribute__((ext_vector_type(4)));

__device__ __forceinline__ unsigned short f2bf(float f) {
  union { float f; unsigned int u; } v; v.f = f;
  return (unsigned short)((v.u + 0x7FFFu + ((v.u >> 16) & 1u)) >> 16);
}

__device__ __forceinline__ void gl_lds16(const float* g, void* l) {
  // async global->LDS DMA: lane i's 16B lands at (wave-uniform l) + i*16
  __builtin_amdgcn_global_load_lds(
      (const __attribute__((address_space(1))) void*)g,
      (__attribute__((address_space(3))) void*)l, 16, 0, 0);
}

__global__ __launch_bounds__(BLK, 4) void fused_kernel(const float* __restrict__ h,
                                                       const int* __restrict__ ids,
                                                       const int* __restrict__ mask,
                                                       const float* __restrict__ W,
                                                       const float* __restrict__ bias,
                                                       float* __restrict__ out) {
  __shared__ __align__(16) unsigned short wlds[48 * WST];   // 74.5 KB, full-K bf16 W
  __shared__ __align__(16) float hbuf[2][16 * 128 * 4];     // 64 KB: 2 bufs x 16 waves x 128 slots x 16B
  __shared__ __align__(16) float s_lds[HID];
  __shared__ float q_lds[48];

  const int tid  = threadIdx.x;
  const int lane = tid & 63, wv = tid >> 6;    // wv in [0,16)
  const int g    = wv & 7,  kh = wv >> 3;      // row-group, K-half
  const int mr   = lane & 15, qd = lane >> 4;
  const int row0 = blockIdx.x * MT;            // flat row = b*512 + s
  const int b    = row0 >> 9;
  const int c0   = kh * HK;

  // wave stages its OWN 16 rows (group g) for chunk c -> barrier-free consumption
  auto issueChunk = [&](int c) {
    int buf = c & 1;
    #pragma unroll
    for (int j = 0; j < 2; ++j) {
      int sw = (j << 6) + lane;                // within-wave slot 0..127
      int rl = sw >> 3;                        // local row 0..15
      int cc = (sw & 7) ^ (rl & 7);            // XOR swizzle (involution)
      const float* gp = h + (size_t)(row0 + (g << 4) + rl) * HID + c * KC + (cc << 2);
      gl_lds16(gp, (void*)&hbuf[buf][((wv << 7) + (j << 6)) << 2]);
    }
  };

  issueChunk(c0); issueChunk(c0 + 1);          // overlap DMA with prologue

  // ---- stage W (bf16, full K); zero pad rows 46,47 ----
  for (int i = tid; i < WST; i += BLK)
    ((unsigned int*)(wlds + 46 * WST))[i] = 0u;
  for (int i = tid; i < (P2 * HID) / 4; i += BLK) {
    int r  = i / 192;
    int cb = (i - r * 192) << 2;
    float4 w4 = *(const float4*)(W + (size_t)r * HID + cb);
    ushort4 v;
    v.x = f2bf(w4.x); v.y = f2bf(w4.y); v.z = f2bf(w4.z); v.w = f2bf(w4.w);
    *(ushort4*)&wlds[r * WST + cb] = v;
  }
  // ---- stage s = h[b,i0,:] + h[b,i1,:] ----
  {
    int i0 = ids[b * 2 + 0], i1 = ids[b * 2 + 1];
    const float* r0 = h + ((size_t)b * SEQ + i0) * HID;
    const float* r1 = h + ((size_t)b * SEQ + i1) * HID;
    if (tid < HID) s_lds[tid] = r0[tid] + r1[tid];
  }
  __syncthreads();

  // ---- q[p] = s . W[p,:] exact fp32, parallel across all 16 waves ----
  #pragma unroll
  for (int t = 0; t < 3; ++t) {
    int p = wv * 3 + t;
    if (p < P2) {
      const float* wp = W + (size_t)p * HID;
      float acc = 0.f;
      #pragma unroll
      for (int j = 0; j < HID / 64; ++j)
        acc += s_lds[(j << 6) + lane] * wp[(j << 6) + lane];
      #pragma unroll
      for (int off = 32; off; off >>= 1)
        acc += __shfl_down(acc, off, 64);
      if (lane == 0) q_lds[p] = acc;           // consumed after reduction barrier
    }
  }

  // ---- barrier-free K-half loop (12 chunks/wave, 2-deep DMA pipeline) ----
  f32x4 acc[3];
  #pragma unroll
  for (int nt = 0; nt < 3; ++nt) acc[nt] = f32x4{0.f, 0.f, 0.f, 0.f};

  const int r7    = mr & 7;
  const int abase = (wv << 7) + (mr << 3);     // slot base of this lane's row

  #pragma unroll
  for (int i = 0; i < HK; ++i) {
    int c = c0 + i;
    if (i < HK - 1) asm volatile("s_waitcnt vmcnt(2)" ::: "memory");
    else            asm volatile("s_waitcnt vmcnt(0)" ::: "memory");
    const float* hb = hbuf[c & 1];
    float4 x0 = *(const float4*)&hb[(abase + (((qd << 1) + 0) ^ r7)) << 2];
    float4 x1 = *(const float4*)&hb[(abase + (((qd << 1) + 1) ^ r7)) << 2];
    bf16x8 a;
    a[0] = (short)f2bf(x0.x); a[1] = (short)f2bf(x0.y);
    a[2] = (short)f2bf(x0.z); a[3] = (short)f2bf(x0.w);
    a[4] = (short)f2bf(x1.x); a[5] = (short)f2bf(x1.y);
    a[6] = (short)f2bf(x1.z); a[7] = (short)f2bf(x1.w);
    #pragma unroll
    for (int nt = 0; nt < 3; ++nt) {
      bf16x8 bb = *(const bf16x8*)&wlds[((nt << 4) + mr) * WST + c * KC + (qd << 3)];
      acc[nt] = __builtin_amdgcn_mfma_f32_16x16x32_bf16(a, bb, acc[nt], 0, 0, 0);
    }
    if (i + 2 < HK) issueChunk(c + 2);
  }

  // ---- combine K-halves via LDS (reuse hbuf), then epilogue by kh=0 waves ----
  __syncthreads();
  float* rb = (float*)hbuf;
  if (kh == 1) {
    #pragma unroll
    for (int nt = 0; nt < 3; ++nt)
      *(f32x4*)&rb[((g << 6) + lane) * 12 + (nt << 2)] = acc[nt];
  }
  __syncthreads();
  if (kh == 0) {
    #pragma unroll
    for (int nt = 0; nt < 3; ++nt)
      acc[nt] += *(const f32x4*)&rb[((g << 6) + lane) * 12 + (nt << 2)];

    int mrow[4];
    #pragma unroll
    for (int i = 0; i < 4; ++i)
      mrow[i] = mask[row0 + (g << 4) + (qd << 2) + i];

    #pragma unroll
    for (int nt = 0; nt < 3; ++nt) {
      int p = (nt << 4) + mr;
      if (p < P2) {
        float bv = bias[p];
        float qv = q_lds[p];
        #pragma unroll
        for (int i = 0; i < 4; ++i) {
          int row = row0 + (g << 4) + (qd << 2) + i;
          float x = acc[nt][i] + bv + (mrow[i] ? qv : 0.f);
          float sg = 1.f / (1.f + __expf(-x));
          sg *= sg; sg *= sg;                 // sigmoid^4
          out[(size_t)row * P2 + p] = sg;
        }
      }
    }
  }
}

extern "C" void kernel_launch(void* const* d_in, const int* in_sizes, int n_in,
                              void* d_out, int out_size, void* d_ws, size_t ws_size,
                              hipStream_t stream) {
  const float* h    = (const float*)d_in[0];   // [64,512,768] fp32
  const int*   ids  = (const int*)d_in[1];     // [64,2]
  const int*   mask = (const int*)d_in[2];     // [64,512]
  const float* W    = (const float*)d_in[3];   // [46,768]
  const float* bias = (const float*)d_in[4];   // [46]
  float* out = (float*)d_out;                  // [64,512,46] fp32

  fused_kernel<<<dim3((64 * SEQ) / MT), BLK, 0, stream>>>(h, ids, mask, W, bias, out);
}